// Round 10
// baseline (333.605 us; speedup 1.0000x reference)
//
#include <hip/hip_runtime.h>
#include <stdint.h>
#include <stddef.h>

// Problem constants (fixed by reference)
#define S_LEN   2048
#define DMODEL  2048
#define NHEADS  16
#define NKVH    8
#define HD      128
// Q prescale folded in at RoPE: HEAD_DIM^-0.5 / 50   (tanh argument scale)
#define QPRE 1.7677669529663688e-3f
// 50*log2(e)
#define C1 72.13475204444817f

typedef __attribute__((ext_vector_type(8))) short  short8;   // 8 x bf16 fragment
typedef __attribute__((ext_vector_type(4))) short  short4v;  // 4 x bf16 fragment
typedef __attribute__((ext_vector_type(4))) float  float4v;  // 4 x f32 accum

static __device__ __forceinline__ unsigned short f2bf(float f) {
  union { float f; unsigned int u; } v; v.f = f;
  unsigned int u = v.u;
  u += 0x7fffu + ((u >> 16) & 1u);   // RNE
  return (unsigned short)(u >> 16);
}
static __device__ __forceinline__ float bf2f(unsigned short b) {
  union { unsigned int u; float f; } v; v.u = ((unsigned int)b) << 16;
  return v.f;
}
static __device__ __forceinline__ void gload_lds16(const void* g, void* l) {
  __builtin_amdgcn_global_load_lds(
      (const __attribute__((address_space(1))) void*)g,
      (__attribute__((address_space(3))) void*)l, 16, 0, 0);
}

// ---------------------------------------------------------------- fp32->bf16
// One launch for all five tensors (x, wq, wk, wv, wo), float4 granularity.
__global__ __launch_bounds__(256) void cvt_all(
    const float* __restrict__ x,  const float* __restrict__ wq,
    const float* __restrict__ wk, const float* __restrict__ wv,
    const float* __restrict__ wo,
    ushort4* __restrict__ xb, ushort4* __restrict__ wcat,
    ushort4* __restrict__ wob) {
  int i = blockIdx.x * 256 + threadIdx.x;
  const float4* src; ushort4* dst; int j;
  if (i < 2097152)      { src = (const float4*)x;  dst = xb;             j = i; }
  else if (i < 3145728) { src = (const float4*)wq; dst = wcat;           j = i - 2097152; }
  else if (i < 3670016) { src = (const float4*)wk; dst = wcat + 1048576; j = i - 3145728; }
  else if (i < 4194304) { src = (const float4*)wv; dst = wcat + 1572864; j = i - 3670016; }
  else                  { src = (const float4*)wo; dst = wob;            j = i - 4194304; }
  float4 v = src[j];
  ushort4 o;
  o.x = f2bf(v.x); o.y = f2bf(v.y); o.z = f2bf(v.z); o.w = f2bf(v.w);
  dst[j] = o;
}

// ---------------------------------------------------------------- GEMM 256² (QKV)
// Barrier-minimal schedule (R5, proven): two sync points per K-tile —
//   (1) lgkmcnt(0)+barrier after last LDS read of A0/A1/B0, then overwrite;
//   (2) counted vmcnt(6)+barrier at tile end.
// Between them 8 waves free-run (ds_reads overlap MFMAs cross-wave).
// T2 XOR swizzle (chunk^=row&7 both sides) keeps bank conflicts at 0.
__global__ __launch_bounds__(512, 2) void gemm256_qkv(
    const unsigned short* __restrict__ A,   // xb  [4096][2048]
    const unsigned short* __restrict__ B,   // wcat[4096][2048] (wq;wk;wv)
    unsigned short* __restrict__ C) {       // QKV region base
  const int t    = threadIdx.x;
  const int lane = t & 63;
  const int w    = t >> 6;        // 0..7
  const int l15  = lane & 15;
  const int quad = lane >> 4;

  const int id  = blockIdx.x;
  const int swz = (id & 7) * 32 + (id >> 3);
  const int m0  = (swz >> 4) * 256;
  const int n0  = (swz & 15) * 256;

  __shared__ unsigned short sm[2][2][2][128 * 64];   // 128 KB

  const int wm  = w >> 2;          // A half (0/1)
  const int wnq = w & 3;           // B quarter
  const int hB  = wnq >> 1;
  const int wnl = (wnq & 1) * 64;

  int soff[2];
#pragma unroll
  for (int i = 0; i < 2; ++i) {
    int P = (w * 2 + i) * 64 + lane;
    int r = P >> 3;
    int lc = (P & 7) ^ (r & 7);
    soff[i] = r * DMODEL + lc * 8;
  }
  const unsigned short* Ab = A + (size_t)m0 * DMODEL;
  const unsigned short* Bb = B + (size_t)n0 * DMODEL;

  auto stage = [&](int mat, int half, int buf, int kt) {
    const unsigned short* g =
        (mat ? Bb : Ab) + (size_t)half * 128 * DMODEL + kt * 64;
    unsigned short* l = &sm[buf][mat][half][(w * 2) * 512];
#pragma unroll
    for (int i = 0; i < 2; ++i)
      gload_lds16(g + soff[i], l + i * 512);
  };

  float4v acc[2][2][4][2];
#pragma unroll
  for (int qm = 0; qm < 2; ++qm)
#pragma unroll
    for (int qn = 0; qn < 2; ++qn)
#pragma unroll
      for (int mt = 0; mt < 4; ++mt)
#pragma unroll
        for (int nt = 0; nt < 2; ++nt)
          acc[qm][qn][mt][nt] = (float4v){0.f, 0.f, 0.f, 0.f};

  // ---- prologue: t0 fully + t1.{A0,A1,B0}; wait t0 landed (t1 in flight)
  stage(0, 0, 0, 0); stage(0, 1, 0, 0); stage(1, 0, 0, 0); stage(1, 1, 0, 0);
  stage(0, 0, 1, 1); stage(0, 1, 1, 1); stage(1, 0, 1, 1);
  asm volatile("s_waitcnt vmcnt(6)" ::: "memory");
  __builtin_amdgcn_s_barrier();

  const int NT = DMODEL / 64;   // 32 K-tiles
#pragma unroll 1
  for (int j = 0; j < NT; ++j) {
    const int c = j & 1;
    const unsigned short* As = &sm[c][0][wm][0];
    const unsigned short* Bs = &sm[c][1][hB][0];
    short8 af[4][2], ag[4][2], bf0[2][2], bf1[2][2];

    if (j + 1 < NT) stage(1, 1, c ^ 1, j + 1);   // t(j+1).B1 (issue early)

    // ---- LDS reads: A lower-half rows + B lower quadrant
#pragma unroll
    for (int mt = 0; mt < 4; ++mt)
#pragma unroll
      for (int kk = 0; kk < 2; ++kk) {
        int r = mt * 16 + l15;
        af[mt][kk] = *(const short8*)&As[r * 64 + (((kk * 4 + quad) ^ (r & 7)) * 8)];
      }
#pragma unroll
    for (int nt = 0; nt < 2; ++nt)
#pragma unroll
      for (int kk = 0; kk < 2; ++kk) {
        int r = wnl + nt * 16 + l15;
        bf0[nt][kk] = *(const short8*)&Bs[r * 64 + (((kk * 4 + quad) ^ (r & 7)) * 8)];
      }
    __builtin_amdgcn_s_setprio(1);
#pragma unroll
    for (int mt = 0; mt < 4; ++mt)
#pragma unroll
      for (int nt = 0; nt < 2; ++nt)
#pragma unroll
        for (int kk = 0; kk < 2; ++kk)
          acc[0][0][mt][nt] = __builtin_amdgcn_mfma_f32_16x16x32_bf16(
              af[mt][kk], bf0[nt][kk], acc[0][0][mt][nt], 0, 0, 0);
    __builtin_amdgcn_s_setprio(0);

    // ---- LDS reads: B upper quadrant
#pragma unroll
    for (int nt = 0; nt < 2; ++nt)
#pragma unroll
      for (int kk = 0; kk < 2; ++kk) {
        int r = wnl + 32 + nt * 16 + l15;
        bf1[nt][kk] = *(const short8*)&Bs[r * 64 + (((kk * 4 + quad) ^ (r & 7)) * 8)];
      }
    __builtin_amdgcn_s_setprio(1);
#pragma unroll
    for (int mt = 0; mt < 4; ++mt)
#pragma unroll
      for (int nt = 0; nt < 2; ++nt)
#pragma unroll
        for (int kk = 0; kk < 2; ++kk)
          acc[0][1][mt][nt] = __builtin_amdgcn_mfma_f32_16x16x32_bf16(
              af[mt][kk], bf1[nt][kk], acc[0][1][mt][nt], 0, 0, 0);
    __builtin_amdgcn_s_setprio(0);

    // ---- LDS reads: A upper-half rows (last reads of A regions)
#pragma unroll
    for (int mt = 0; mt < 4; ++mt)
#pragma unroll
      for (int kk = 0; kk < 2; ++kk) {
        int r = 64 + mt * 16 + l15;
        ag[mt][kk] = *(const short8*)&As[r * 64 + (((kk * 4 + quad) ^ (r & 7)) * 8)];
      }
    // sync point (1): all LDS reads of A0/A1/B0 complete block-wide,
    // then overwrite them with t(j+2)'s DMA.
    asm volatile("s_waitcnt lgkmcnt(0)" ::: "memory");
    __builtin_amdgcn_s_barrier();
    if (j + 2 < NT) {
      stage(0, 0, c, j + 2); stage(0, 1, c, j + 2); stage(1, 0, c, j + 2);
    }
    __builtin_amdgcn_s_setprio(1);
#pragma unroll
    for (int mt = 0; mt < 4; ++mt)
#pragma unroll
      for (int nt = 0; nt < 2; ++nt)
#pragma unroll
        for (int kk = 0; kk < 2; ++kk)
          acc[1][0][mt][nt] = __builtin_amdgcn_mfma_f32_16x16x32_bf16(
              ag[mt][kk], bf0[nt][kk], acc[1][0][mt][nt], 0, 0, 0);
#pragma unroll
    for (int mt = 0; mt < 4; ++mt)
#pragma unroll
      for (int nt = 0; nt < 2; ++nt)
#pragma unroll
        for (int kk = 0; kk < 2; ++kk)
          acc[1][1][mt][nt] = __builtin_amdgcn_mfma_f32_16x16x32_bf16(
              ag[mt][kk], bf1[nt][kk], acc[1][1][mt][nt], 0, 0, 0);
    __builtin_amdgcn_s_setprio(0);
    // sync point (2): retire all of t(j+1)'s DMA; keep t(j+2) in flight.
    if (j + 2 < NT)      { asm volatile("s_waitcnt vmcnt(6)" ::: "memory"); }
    else if (j + 1 < NT) { asm volatile("s_waitcnt vmcnt(0)" ::: "memory"); }
    __builtin_amdgcn_s_barrier();
  }

  // ---- epilogue: fused QKV scatter
#pragma unroll
  for (int qm = 0; qm < 2; ++qm)
#pragma unroll
    for (int mt = 0; mt < 4; ++mt) {
      int row0 = m0 + wm * 128 + qm * 64 + mt * 16 + quad * 4;
      int b = row0 >> 11, s0 = row0 & (S_LEN - 1);
#pragma unroll
      for (int qn = 0; qn < 2; ++qn)
#pragma unroll
        for (int nt = 0; nt < 2; ++nt) {
          int col = n0 + wnq * 64 + qn * 32 + nt * 16 + l15;
          float4v v = acc[qm][qn][mt][nt];
          if (col < 2048) {            // Q: [b][16][s][128]
            int head = col >> 7, d = col & (HD - 1);
#pragma unroll
            for (int r2 = 0; r2 < 4; ++r2)
              C[((size_t)(b * 16 + head) * S_LEN + s0 + r2) * HD + d] = f2bf(v[r2]);
          } else if (col < 3072) {     // K: offset 8388608 el
            int c2 = col - 2048;
            int kvh = c2 >> 7, d = c2 & (HD - 1);
#pragma unroll
            for (int r2 = 0; r2 < 4; ++r2)
              C[8388608 + ((size_t)(b * 8 + kvh) * S_LEN + s0 + r2) * HD + d] = f2bf(v[r2]);
          } else {                     // V^T: offset 12582912 el
            int c2 = col - 3072;
            int kvh = c2 >> 7, d = c2 & (HD - 1);
            ushort4 pk;
            pk.x = f2bf(v[0]); pk.y = f2bf(v[1]);
            pk.z = f2bf(v[2]); pk.w = f2bf(v[3]);
            *(ushort4*)&C[12582912 + ((size_t)(b * 8 + kvh) * HD + d) * S_LEN + s0] = pk;
          }
        }
    }
}

// ---------------------------------------------------------------- GEMM 256x128 (output proj)
// Final projection on the proven barrier-minimal schedule (R9).
// C[4096,2048] = AO[4096,2048] @ wob[2048,2048]^T, fp32 out.
// BM=256, BN=128, BK=64 -> grid 16x16 = 256 blocks = 1/CU.
__global__ __launch_bounds__(512, 2) void gemm256_out(
    const unsigned short* __restrict__ A,   // AO  [4096][2048]
    const unsigned short* __restrict__ B,   // wob [2048][2048]
    float* __restrict__ C) {                // [4096][2048] fp32
  const int t    = threadIdx.x;
  const int lane = t & 63;
  const int w    = t >> 6;        // 0..7
  const int l15  = lane & 15;
  const int quad = lane >> 4;

  const int id  = blockIdx.x;
  const int swz = (id & 7) * 32 + (id >> 3);   // XCD-aware, 256%8==0 bijective
  const int m0  = (swz >> 4) * 256;
  const int n0  = (swz & 15) * 128;

  __shared__ unsigned short sm[2][3][128 * 64];   // 96 KB: [buf][A0,A1,B]

  const int wm = w >> 1;          // M quarter (0..3), 64 rows each
  const int wn = w & 1;           // N half (0..1), 64 cols each
  const int hA = wm >> 1;         // A staging half (0/1)
  const int ra0 = (wm & 1) * 64;  // local row base within A half

  int soff[2];
#pragma unroll
  for (int i = 0; i < 2; ++i) {
    int P = (w * 2 + i) * 64 + lane;
    int r = P >> 3;
    int lc = (P & 7) ^ (r & 7);
    soff[i] = r * DMODEL + lc * 8;
  }
  const unsigned short* Ab = A + (size_t)m0 * DMODEL;
  const unsigned short* Bb = B + (size_t)n0 * DMODEL;

  // region: 0 = A rows 0-127, 1 = A rows 128-255, 2 = B rows 0-127
  auto stage = [&](int region, int buf, int kt) {
    const unsigned short* g =
        (region == 2 ? Bb : Ab + (size_t)region * 128 * DMODEL) + kt * 64;
    unsigned short* l = &sm[buf][region][(w * 2) * 512];
#pragma unroll
    for (int i = 0; i < 2; ++i)
      gload_lds16(g + soff[i], l + i * 512);
  };

  float4v acc[4][4];
#pragma unroll
  for (int mt = 0; mt < 4; ++mt)
#pragma unroll
    for (int nt = 0; nt < 4; ++nt)
      acc[mt][nt] = (float4v){0.f, 0.f, 0.f, 0.f};

  // ---- prologue: t0 (6 loads) + t1 (6 loads); retire t0, t1 in flight
  stage(0, 0, 0); stage(1, 0, 0); stage(2, 0, 0);
  stage(0, 1, 1); stage(1, 1, 1); stage(2, 1, 1);
  asm volatile("s_waitcnt vmcnt(6)" ::: "memory");
  __builtin_amdgcn_s_barrier();

  const int NT = DMODEL / 64;   // 32 K-tiles
#pragma unroll 1
  for (int j = 0; j < NT; ++j) {
    const int c = j & 1;
    const unsigned short* As = &sm[c][hA][0];
    const unsigned short* Bs = &sm[c][2][0];
    short8 af[4][2], bf[4][2];

    // ---- LDS reads: wave's 64 A rows + 64 B rows (all reads of tile j)
#pragma unroll
    for (int mt = 0; mt < 4; ++mt)
#pragma unroll
      for (int kk = 0; kk < 2; ++kk) {
        int r = ra0 + mt * 16 + l15;
        af[mt][kk] = *(const short8*)&As[r * 64 + (((kk * 4 + quad) ^ (r & 7)) * 8)];
      }
#pragma unroll
    for (int nt = 0; nt < 4; ++nt)
#pragma unroll
      for (int kk = 0; kk < 2; ++kk) {
        int r = wn * 64 + nt * 16 + l15;
        bf[nt][kk] = *(const short8*)&Bs[r * 64 + (((kk * 4 + quad) ^ (r & 7)) * 8)];
      }
    // sync point (1): all reads of buf c complete block-wide, then overwrite
    asm volatile("s_waitcnt lgkmcnt(0)" ::: "memory");
    __builtin_amdgcn_s_barrier();
    if (j + 2 < NT) { stage(0, c, j + 2); stage(1, c, j + 2); stage(2, c, j + 2); }

    __builtin_amdgcn_s_setprio(1);
#pragma unroll
    for (int mt = 0; mt < 4; ++mt)
#pragma unroll
      for (int nt = 0; nt < 4; ++nt)
#pragma unroll
        for (int kk = 0; kk < 2; ++kk)
          acc[mt][nt] = __builtin_amdgcn_mfma_f32_16x16x32_bf16(
              af[mt][kk], bf[nt][kk], acc[mt][nt], 0, 0, 0);
    __builtin_amdgcn_s_setprio(0);

    // sync point (2): retire t(j+1)'s 6 loads; keep t(j+2)'s 6 in flight.
    if (j + 2 < NT)      { asm volatile("s_waitcnt vmcnt(6)" ::: "memory"); }
    else if (j + 1 < NT) { asm volatile("s_waitcnt vmcnt(0)" ::: "memory"); }
    __builtin_amdgcn_s_barrier();
  }

  // ---- epilogue: fp32 row-major write
#pragma unroll
  for (int mt = 0; mt < 4; ++mt) {
    int row = m0 + wm * 64 + mt * 16 + quad * 4;
#pragma unroll
    for (int nt = 0; nt < 4; ++nt) {
      int col = n0 + wn * 64 + nt * 16 + l15;
#pragma unroll
      for (int r2 = 0; r2 < 4; ++r2)
        C[(size_t)(row + r2) * 2048 + col] = acc[mt][nt][r2];
    }
  }
}

// ---------------------------------------------------------------- RoPE (Gemma2)
__global__ __launch_bounds__(256) void rope_kernel(unsigned short* __restrict__ Q,
                                                   unsigned short* __restrict__ Kc) {
  int gt = blockIdx.x * 256 + threadIdx.x;
  int r = gt >> 6;        // row id over Q rows then K rows
  int j = gt & 63;        // pair index
  const int QROWS = 2 * NHEADS * S_LEN;
  bool isQ = (r < QROWS);
  unsigned short* p = isQ ? (Q + (size_t)r * HD)
                          : (Kc + (size_t)(r - QROWS) * HD);
  int pos = r & (S_LEN - 1);
  float inv = exp2f(-(float)j * 0.20762050593046868f);  // 10000^(-j/64)
  float ang = (float)pos * inv;
  float c = cosf(ang), s = sinf(ang);
  float sc = isQ ? QPRE : 1.0f;
  float x1 = bf2f(p[j]), x2 = bf2f(p[j + 64]);
  p[j]      = f2bf((x1 * c - x2 * s) * sc);
  p[j + 64] = f2bf((x2 * c + x1 * s) * sc);
}

// ---------------------------------------------------------------- attention
// R10: P-IN-REGISTER PV via mfma_16x16x16. R9 accounting: attn is ~82%
// LDS-throughput-bound (192 KB/block-iter: K 64 + V 64 + P 32 + staging 32).
// The P LDS round-trip existed only to re-layout QK^T output (lane holds
// P[k=quad*4+r][q=l15]) into the K=32 PV operand (k=quad*8..+7, cross-lane).
// But mfma_f32_16x16x16 B-operand layout is EXACTLY col=l15, k=quad*4..+3 —
// our registers as-is. PV becomes O^T[d][q] += mfma16(A=V^T b64 frag,
// B=P-frag in-register) per ntk (K=16): P never touches LDS (-17% traffic),
// Pt buffer deleted (LDS 48->32 KB), perm-pack now feeds the operand
// directly. Output flips to O^T per-lane: epilogue q=l15 -> lane's own
// inv (no iv shuffle), ushort4 d-contiguous stores (same 32B segments).
// V bytes unchanged (32 b64 = 16 KB/wave-iter); PV FLOPs unchanged
// (64 half-size MFMAs). Score+PV fused per ntk (P in regs, no barrier).
// Geometry unchanged from R5 (proven): paired tiles A=pp/B=31-pp, 4 waves,
// single-buffered K/V, 2 barriers/iter. Softcap: clamp |x|<=0.26, tanh
// poly, p = exp2(C1*t). K/V tiles XOR-swizzled (chunk ^= row&7).
__global__ __launch_bounds__(256, 2) void attn_kernel(
    const unsigned short* __restrict__ Q,   // [b][16][s][128] (prescaled)
    const unsigned short* __restrict__ Kc,  // [b][8][s][128]
    const unsigned short* __restrict__ Vt,  // [b][8][128][s]
    unsigned short* __restrict__ Aout) {    // [b][s][2048]
  const int t    = threadIdx.x;
  const int lane = t & 63;
  const int w    = t >> 6;          // 0..3
  const int l15  = lane & 15;
  const int quad = lane >> 4;
  const int bh = blockIdx.x;
  const int pp = blockIdx.y;
  const int b = bh >> 4, h = bh & 15, kv = h >> 1;
  const int qtA = pp, qtB = 31 - pp;
  const int q0A = qtA * 64, q0B = qtB * 64;
  const int ntB = qtB + 1;   // key tiles for B (superset of A's)

  __shared__ unsigned short Kt[64 * 128];      // 16 KB, [key][hd]
  __shared__ unsigned short Vts[128 * 64];     // 16 KB, [hd][key]

  // Staging source offsets (swizzle on source side; global_load_lds dest is
  // wave-uniform base + lane*16). 256 threads: 4 chunks each per tensor.
  int offK[4], offV[4];
#pragma unroll
  for (int i = 0; i < 4; ++i) {
    int g = i * 256 + t;
    int rK = g >> 4, cK = (g & 15) ^ (rK & 7);
    offK[i] = rK * HD + cK * 8;
    int rV = g >> 3, cV = (g & 7) ^ (rV & 7);
    offV[i] = rV * S_LEN + cV * 8;
  }

  // Q fragments (B-operand: l15 = q_local, k = kk*32+quad*8)
  const unsigned short* QA = Q + ((size_t)(b * NHEADS + h) * S_LEN + q0A + w * 16) * HD;
  const unsigned short* QB = Q + ((size_t)(b * NHEADS + h) * S_LEN + q0B + w * 16) * HD;
  short8 qfA[4], qfB[4];
#pragma unroll
  for (int kk = 0; kk < 4; ++kk) {
    qfA[kk] = *(const short8*)&QA[l15 * HD + kk * 32 + quad * 8];
    qfB[kk] = *(const short8*)&QB[l15 * HD + kk * 32 + quad * 8];
  }

  // O^T accumulators: lane(l15,quad) reg r2 = O[q=l15][d=nth*16+quad*4+r2]
  float4v oA[8], oB[8];
#pragma unroll
  for (int nth = 0; nth < 8; ++nth) {
    oA[nth] = (float4v){0.f, 0.f, 0.f, 0.f};
    oB[nth] = (float4v){0.f, 0.f, 0.f, 0.f};
  }
  float lsA = 0.f, lsB = 0.f;

  const unsigned short* kg0 = Kc + (size_t)(b * NKVH + kv) * S_LEN * HD;
  const unsigned short* vg0 = Vt + (size_t)(b * NKVH + kv) * HD * S_LEN;

  auto stage = [&](int kt) {
    const unsigned short* kgp = kg0 + (size_t)kt * 64 * HD;
    const unsigned short* vgp = vg0 + (size_t)kt * 64;
#pragma unroll
    for (int i = 0; i < 4; ++i)
      gload_lds16(kgp + offK[i], &Kt[(i * 256 + w * 64) * 8]);
#pragma unroll
    for (int i = 0; i < 4; ++i)
      gload_lds16(vgp + offV[i], &Vts[(i * 256 + w * 64) * 8]);
  };

  // softcap: p = exp2(C1 * tanh_poly(x))
  auto softcap = [&](float x) -> float {
    float xx = __builtin_amdgcn_fmed3f(x, -0.26f, 0.26f);
    float x2 = xx * xx;
    float u = __builtin_fmaf(0.13333334f, x2, -0.33333334f);
    float v = __builtin_fmaf(u, x2, 1.0f);
    return __builtin_amdgcn_exp2f((C1 * xx) * v);
  };

  stage(0);
  for (int kt = 0; kt < ntB; ++kt) {
    __syncthreads();   // staging of kt complete (vmcnt drains at barrier)
    const bool doA   = (kt <= qtA);
    const bool diagA = (kt == qtA);
    const bool diagB = (kt == qtB);

    // ---- fused score+PV per ntk group (16 keys each; P stays in registers)
#pragma unroll
    for (int ntk = 0; ntk < 4; ++ntk) {
      const bool mB = !(diagB && (ntk * 16 > w * 16 + 15));
      const bool mA = doA && !(diagA && (ntk * 16 > w * 16 + 15));
      if (!(mB || mA)) continue;

      short8 kf[4];
#pragma unroll
      for (int kk = 0; kk < 4; ++kk)
        kf[kk] = *(const short8*)
            &Kt[(ntk * 16 + l15) * HD + (((kk * 4 + quad) ^ (l15 & 7)) * 8)];

      short4v pB, pA;
      if (mB) {
        float4v s0 = (float4v){0.f, 0.f, 0.f, 0.f};
#pragma unroll
        for (int kk = 0; kk < 4; ++kk)
          s0 = __builtin_amdgcn_mfma_f32_16x16x32_bf16(kf[kk], qfB[kk], s0, 0, 0, 0);
        float pv[4];
#pragma unroll
        for (int r = 0; r < 4; ++r) {
          float p = softcap(s0[r]);
          if (diagB)
            p = (ntk * 16 + quad * 4 + r <= w * 16 + l15) ? p : 0.f;
          lsB += p;
          pv[r] = p;
        }
        union { float f; unsigned u; } u0, u1, u2, u3;
        u0.f = pv[0]; u1.f = pv[1]; u2.f = pv[2]; u3.f = pv[3];
        union { unsigned u[2]; short4v s; } pk;
        pk.u[0] = __builtin_amdgcn_perm(u1.u, u0.u, 0x07060302);  // [bf16(p0),bf16(p1)]
        pk.u[1] = __builtin_amdgcn_perm(u3.u, u2.u, 0x07060302);  // [bf16(p2),bf16(p3)]
        pB = pk.s;
      }
      if (mA) {
        float4v s0 = (float4v){0.f, 0.f, 0.f, 0.f};
#pragma unroll
        for (int kk = 0; kk < 4; ++kk)
          s0 = __builtin_amdgcn_mfma_f32_16x16x32_bf16(kf[kk], qfA[kk], s0, 0, 0, 0);
        float pv[4];
#pragma unroll
        for (int r = 0; r < 4; ++r) {
          float p = softcap(s0[r]);
          if (diagA)
            p = (ntk * 16 + quad * 4 + r <= w * 16 + l15) ? p : 0.f;
          lsA += p;
          pv[r] = p;
        }
        union { float f; unsigned u; } u0, u1, u2, u3;
        u0.f = pv[0]; u1.f = pv[1]; u2.f = pv[2]; u3.f = pv[3];
        union { unsigned u[2]; short4v s; } pk;
        pk.u[0] = __builtin_amdgcn_perm(u1.u, u0.u, 0x07060302);
        pk.u[1] = __builtin_amdgcn_perm(u3.u, u2.u, 0x07060302);
        pA = pk.s;
      }

      // ---- PV for this ntk: A = V^T frag (b64), B = P frag (register)
      //      D[d=quad*4+r2][q=l15] accumulates O^T. vf shared A/B tiles.
#pragma unroll
      for (int nth = 0; nth < 8; ++nth) {
        int row = nth * 16 + l15;
        int caddr = row * 64 + (((ntk * 2 + (quad >> 1)) ^ (l15 & 7)) * 8)
                    + (quad & 1) * 4;
        short4v vf = *(const short4v*)&Vts[caddr];
        if (mB)
          oB[nth] = __builtin_amdgcn_mfma_f32_16x16x16bf16_1k(vf, pB, oB[nth], 0, 0, 0);
        if (mA)
          oA[nth] = __builtin_amdgcn_mfma_f32_16x16x16bf16_1k(vf, pA, oA[nth], 0, 0, 0);
      }
    }

    __syncthreads();   // all waves done reading Kt/Vts before restage
    if (kt + 1 < ntB) stage(kt + 1);
  }

  // ---- epilogues (both tiles; lane's q = l15, O^T layout)
#pragma unroll
  for (int tile = 0; tile < 2; ++tile) {
    float ls = tile ? lsA : lsB;
    float4v* oo = tile ? oA : oB;
    int q0 = tile ? q0A : q0B;
    float v = ls;
    v += __shfl_xor(v, 16, 64);
    v += __shfl_xor(v, 32, 64);
    float inv = __builtin_amdgcn_rcpf(v);   // denominator for q = l15
    unsigned short* ob = Aout + (size_t)(b * S_LEN + q0 + w * 16 + l15) * DMODEL
                         + h * HD + quad * 4;
#pragma unroll
    for (int nth = 0; nth < 8; ++nth) {
      ushort4 st;
      st.x = f2bf(oo[nth][0] * inv);
      st.y = f2bf(oo[nth][1] * inv);
      st.z = f2bf(oo[nth][2] * inv);
      st.w = f2bf(oo[nth][3] * inv);
      *(ushort4*)&ob[nth * 16] = st;
    }
  }
}

// ---------------------------------------------------------------- launch
extern "C" void kernel_launch(void* const* d_in, const int* in_sizes, int n_in,
                              void* d_out, int out_size, void* d_ws, size_t ws_size,
                              hipStream_t stream) {
  const float* x  = (const float*)d_in[0];
  const float* wq = (const float*)d_in[1];
  const float* wk = (const float*)d_in[2];
  const float* wv = (const float*)d_in[3];
  const float* wo = (const float*)d_in[4];

  char* ws = (char*)d_ws;
  unsigned short* xb   = (unsigned short*)(ws + 0);          // 16 MB x bf16 [4096][2048]
  unsigned short* wcat = (unsigned short*)(ws + 16777216);   // 16 MB [wq;wk;wv] rows
  unsigned short* wob  = (unsigned short*)(ws + 33554432);   // 8 MB
  unsigned short* QKV  = (unsigned short*)(ws + 41943040);   // 32 MB Q|K|V^T contiguous
  unsigned short* AO   = (unsigned short*)(ws + 75497472);   // 16 MB [4096][2048]

  unsigned short* Qw = QKV;
  unsigned short* Kw = QKV + 8388608;
  unsigned short* Vw = QKV + 12582912;

  cvt_all<<<20480, 256, 0, stream>>>(x, wq, wk, wv, wo,
                                     (ushort4*)xb, (ushort4*)wcat, (ushort4*)wob);

  // Fused QKV projection: 256² barrier-minimal pipeline
  gemm256_qkv<<<256, 512, 0, stream>>>(xb, wcat, QKV);

  rope_kernel<<<24576, 256, 0, stream>>>(Qw, Kw);

  attn_kernel<<<dim3(32, 16), 256, 0, stream>>>(Qw, Kw, Vw, AO);

  // Final projection: 256x128-tile barrier-minimal pipeline (256 blocks = 1/CU)
  gemm256_out<<<256, 512, 0, stream>>>(AO, wob, (float*)d_out);
}